// Round 2
// baseline (243.163 us; speedup 1.0000x reference)
//
#include <hip/hip_runtime.h>
#include <cstdint>
#include <cstddef>

// Problem constants: B=1024, T=12, D=512
#define Bsz 1024
#define Tsz 12
#define Dsz 512

#define BM 128           // j tile (rows of P)
#define BN 128           // i tile (rows of X)
#define BKg 32           // K-chunk per stage
#define NIB (Bsz / BN)   // 8 i-tiles
#define NJB (Bsz / BM)   // 8 j-tiles
#define NGRP (Tsz * NJB) // 96 (t, jb) groups

typedef _Float16 h4     __attribute__((ext_vector_type(4)));
typedef _Float16 f16x8  __attribute__((ext_vector_type(8)));
typedef float    f32x4  __attribute__((ext_vector_type(4)));
typedef float    f32x16 __attribute__((ext_vector_type(16)));

// fp32 -> f16 hi/lo split (hi = rne(x), lo = rne(x - hi)); hi*hi / hi*lo /
// lo*hi accumulate in fp32 inside the MFMA; dropped lo*lo ~2^-22 relative.
__device__ __forceinline__ void cvt_store(const float4 v, _Float16* hp, _Float16* lp) {
    _Float16 hx = (_Float16)v.x, hy = (_Float16)v.y,
             hz = (_Float16)v.z, hw = (_Float16)v.w;
    h4 hh = {hx, hy, hz, hw};
    h4 ll = {(_Float16)(v.x - (float)hx), (_Float16)(v.y - (float)hy),
             (_Float16)(v.z - (float)hz), (_Float16)(v.w - (float)hw)};
    *(h4*)hp = hh;
    *(h4*)lp = ll;
}

// async global->LDS, 16B per lane; LDS dest is wave-uniform base + lane*16.
__device__ __forceinline__ void gload_lds16(const _Float16* g, _Float16* l) {
    __builtin_amdgcn_global_load_lds(
        (const __attribute__((address_space(1))) void*)g,
        (__attribute__((address_space(3))) void*)l, 16, 0, 0);
}

// One-time fp32 -> f16 hi/lo conversion, layout transposed to [T][B][D] so a
// GEMM tile's rows are contiguous per t. Also zeroes out[] and the tickets.
__global__ __launch_bounds__(256) void convert_kernel(
    const float* __restrict__ P, const float* __restrict__ X,
    _Float16* __restrict__ Ph, _Float16* __restrict__ Pl,
    _Float16* __restrict__ Xh, _Float16* __restrict__ Xl,
    float* __restrict__ out, int* __restrict__ tickets)
{
    const int gtid = blockIdx.x * 256 + threadIdx.x;
    if (gtid < 2) out[gtid] = 0.0f;
    if (gtid < NGRP) tickets[gtid] = 0;
    const int nf4 = Bsz * Tsz * (Dsz / 4);       // 1,572,864 float4 per tensor
    for (int f = gtid; f < nf4; f += gridDim.x * 256) {
        const int row = f >> 7;                  // / (D/4 = 128)
        const int d4  = f & 127;
        const int b   = row / Tsz;
        const int t   = row - b * Tsz;
        const size_t oi = ((size_t)t * Bsz + b) * Dsz + (size_t)d4 * 4;
        const float4 pv = ((const float4*)P)[f];
        cvt_store(pv, &Ph[oi], &Pl[oi]);
        const float4 xv = ((const float4*)X)[f];
        cvt_store(xv, &Xh[oi], &Xl[oi]);
    }
}

// Fused GEMM + tile softmax-partials + last-tile combine.
// dots[t,i,j] = <P[j,t,:], X[i,t,:]>. 128x128 tile, 4 waves (2x2 of 64x64).
// 32x32x16 MFMA (24 issues/K-step vs 48 at 16x16x32). Staging via
// global_load_lds dwordx4 with XOR granule swizzle on the GLOBAL source
// (linear LDS dest) + same XOR on ds_read -> conflict-free (3072 last round).
// XCD-chunked bijective blockid swizzle: each XCD gets 96 consecutive
// t-major tiles -> per-t working set (4 MB) is L2-resident on one XCD.
__global__ __launch_bounds__(256, 3) void gemm_fused_kernel(
    const _Float16* __restrict__ Phg, const _Float16* __restrict__ Plg,
    const _Float16* __restrict__ Xhg, const _Float16* __restrict__ Xlg,
    float* pm,        // [Tsz*Bsz*NIB] tile max
    float* ps,        // [Tsz*Bsz*NIB] tile sum exp
    int*   pa,        // [Tsz*Bsz*NIB] tile argmax (global i)
    float* diag,      // [Tsz*Bsz]
    int*   tickets,   // [NGRP]
    float* out)       // [2]
{
    // ---- XCD-chunked bijective remap (768 % 8 == 0) ----
    const int orig = blockIdx.x + (blockIdx.y << 3) + (blockIdx.z << 6);
    const int wgid = (orig & 7) * 96 + (orig >> 3);
    const int t   = wgid >> 6;       // t-major: 64 tiles per t-plane
    const int rem = wgid & 63;
    const int by  = rem >> 3;        // j tile
    const int bx  = rem & 7;         // i tile (fastest -> P-tile reuse in L2)
    const int ib = bx * BN;
    const int jb = by * BM;

    const int tid  = threadIdx.x;
    const int lane = tid & 63;
    const int w    = tid >> 6;          // wave 0..3
    const int jw   = (w >> 1) * 64;     // wave j-offset
    const int iw   = (w & 1) * 64;      // wave i-offset
    const int ml32 = lane & 31;
    const int half = lane >> 5;
    const int sw   = (ml32 >> 1) & 3;   // ds_read granule swizzle key

    __shared__ _Float16 Lds[4][BM][BKg];   // 0=Ph 1=Pl 2=Xh 3=Xl, 8KB each
    __shared__ float sm_m[BM][2];
    __shared__ float sm_s[BM][2];
    __shared__ int   sm_a[BM][2];
    __shared__ int   lastFlag;

    f32x16 acc[2][2];
#pragma unroll
    for (int r = 0; r < 2; ++r)
#pragma unroll
        for (int c = 0; c < 2; ++c)
#pragma unroll
            for (int v = 0; v < 16; ++v) acc[r][c][v] = 0.0f;

    // ---- staging setup: wave w owns array w; 8 instrs stage 128 rows x 32 k ----
    const _Float16* tb = (w == 0) ? Phg : (w == 1) ? Plg : (w == 2) ? Xhg : Xlg;
    const int rb = (w < 2) ? jb : ib;
    // lane l -> row = h*16 + (l>>2), granule pos g' = l&3; source granule
    // g = g' ^ ((row>>1)&3) = (l&3) ^ ((l>>3)&3)
    const _Float16* gbase = tb + ((size_t)t * Bsz + rb) * Dsz
                          + (size_t)(lane >> 2) * Dsz
                          + (((lane & 3) ^ ((lane >> 3) & 3)) << 3);

    const int g0 = (half ^ sw) << 3;     // f16 offset of k-half 0 granule
    // k-half 1 granule = (g'^2) -> f16 offset g0 ^ (2<<3)

    for (int k0 = 0; k0 < Dsz; k0 += BKg) {
#pragma unroll
        for (int h = 0; h < 8; ++h)
            gload_lds16(gbase + (size_t)(h * 16) * Dsz + k0, &Lds[w][h * 16][0]);
        __syncthreads();

        // ---- fragments (swizzled reads, conflict-free) ----
        // A/B layout 32x32x16: row = lane&31, k = (lane>>5)*8 + e (+16 for kk=1)
        f16x8 ah[2][2], al[2][2], bh[2][2], bl[2][2];
#pragma unroll
        for (int r = 0; r < 2; ++r) {
            const int row = jw + r * 32 + ml32;
            ah[r][0] = *(const f16x8*)&Lds[0][row][g0];
            ah[r][1] = *(const f16x8*)&Lds[0][row][g0 ^ 16];
            al[r][0] = *(const f16x8*)&Lds[1][row][g0];
            al[r][1] = *(const f16x8*)&Lds[1][row][g0 ^ 16];
        }
#pragma unroll
        for (int c = 0; c < 2; ++c) {
            const int row = iw + c * 32 + ml32;
            bh[c][0] = *(const f16x8*)&Lds[2][row][g0];
            bh[c][1] = *(const f16x8*)&Lds[2][row][g0 ^ 16];
            bl[c][0] = *(const f16x8*)&Lds[3][row][g0];
            bl[c][1] = *(const f16x8*)&Lds[3][row][g0 ^ 16];
        }

        // ---- MFMA: hi*hi + hi*lo + lo*hi per k-half ----
#pragma unroll
        for (int r = 0; r < 2; ++r)
#pragma unroll
            for (int c = 0; c < 2; ++c)
#pragma unroll
                for (int kk = 0; kk < 2; ++kk) {
                    acc[r][c] = __builtin_amdgcn_mfma_f32_32x32x16_f16(ah[r][kk], bh[c][kk], acc[r][c], 0, 0, 0);
                    acc[r][c] = __builtin_amdgcn_mfma_f32_32x32x16_f16(ah[r][kk], bl[c][kk], acc[r][c], 0, 0, 0);
                    acc[r][c] = __builtin_amdgcn_mfma_f32_32x32x16_f16(al[r][kk], bh[c][kk], acc[r][c], 0, 0, 0);
                }
        __syncthreads();
    }

    // C/D layout 32x32: col = lane&31, row = (v&3) + 8*(v>>2) + 4*(lane>>5)

    // ---- diag extraction (global index test; epilogue-only) ----
#pragma unroll
    for (int r = 0; r < 2; ++r)
#pragma unroll
        for (int v = 0; v < 16; ++v) {
            const int jg = jb + jw + r * 32 + (v & 3) + 8 * (v >> 2) + 4 * half;
#pragma unroll
            for (int c = 0; c < 2; ++c) {
                const int ig = ib + iw + c * 32 + ml32;
                if (ig == jg) diag[(size_t)t * Bsz + jg] = acc[r][c][v];
            }
        }

    // ---- per-row (j) partial over this wave's 64-i slice ----
#pragma unroll
    for (int r = 0; r < 2; ++r)
#pragma unroll
        for (int v = 0; v < 16; ++v) {
            float m = acc[r][0][v];
            int   ai = iw + ml32;
            {
                const float val = acc[r][1][v];
                if (val > m) { m = val; ai = iw + 32 + ml32; }  // ties keep smaller i
            }
#pragma unroll
            for (int off = 1; off < 32; off <<= 1) {   // reduce over lane&31 only
                const float om = __shfl_xor(m, off);
                const int   oi = __shfl_xor(ai, off);
                if (om > m || (om == m && oi < ai)) { m = om; ai = oi; }
            }
            float s = __expf(acc[r][0][v] - m) + __expf(acc[r][1][v] - m);
#pragma unroll
            for (int off = 1; off < 32; off <<= 1) s += __shfl_xor(s, off);

            if (ml32 == 0) {   // lanes 0 and 32 hold different rows (half)
                const int row = jw + r * 32 + (v & 3) + 8 * (v >> 2) + 4 * half;
                sm_m[row][iw >> 6] = m;
                sm_s[row][iw >> 6] = s;
                sm_a[row][iw >> 6] = ib + ai;   // global i
            }
        }
    __syncthreads();

    // ---- combine the two i-halves, write tile partials ----
    if (tid < BM) {
        const int row = tid;
        const float m0 = sm_m[row][0], m1 = sm_m[row][1];
        const float s0 = sm_s[row][0], s1 = sm_s[row][1];
        float M; int A;
        if (m1 > m0) { M = m1; A = sm_a[row][1]; }   // tie -> half 0 (smaller i)
        else         { M = m0; A = sm_a[row][0]; }
        const float S = s0 * __expf(m0 - M) + s1 * __expf(m1 - M);
        const size_t slot = ((size_t)t * Bsz + (jb + row)) * NIB + bx;
        pm[slot] = M;
        ps[slot] = S;
        pa[slot] = A;
    }

    // ---- last-tile-in-group does the cross-tile combine (saves a dispatch) ----
    __threadfence();          // release our partials (agent scope, L2 writeback)
    __syncthreads();
    if (tid == 0) {
        const int prev = __hip_atomic_fetch_add(&tickets[t * NJB + by], 1,
                                                __ATOMIC_ACQ_REL,
                                                __HIP_MEMORY_SCOPE_AGENT);
        lastFlag = (prev == NIB - 1);
    }
    __syncthreads();
    if (!lastFlag) return;
    __threadfence();          // acquire side for all threads

    if (tid < BM) {
        const int j   = jb + tid;
        const int col = t * Bsz + j;
        const size_t base = (size_t)col * NIB;
        float pmv[NIB], psv[NIB];
        int   pav[NIB];
#pragma unroll
        for (int b = 0; b < NIB; ++b) {
            pmv[b] = __hip_atomic_load(&pm[base + b], __ATOMIC_RELAXED, __HIP_MEMORY_SCOPE_AGENT);
            psv[b] = __hip_atomic_load(&ps[base + b], __ATOMIC_RELAXED, __HIP_MEMORY_SCOPE_AGENT);
            pav[b] = __hip_atomic_load(&pa[base + b], __ATOMIC_RELAXED, __HIP_MEMORY_SCOPE_AGENT);
        }
        float M = pmv[0]; int A = pav[0];
#pragma unroll
        for (int b = 1; b < NIB; ++b)
            if (pmv[b] > M) { M = pmv[b]; A = pav[b]; }   // ties -> smaller i
        float S = 0.0f;
#pragma unroll
        for (int b = 0; b < NIB; ++b) S += psv[b] * __expf(pmv[b] - M);

        const float lse = M + logf(S);
        const float dv  = __hip_atomic_load(&diag[col], __ATOMIC_RELAXED, __HIP_MEMORY_SCOPE_AGENT);
        float sl = lse - dv;
        float sc = (A == j) ? 1.0f : 0.0f;

#pragma unroll
        for (int off = 1; off < 64; off <<= 1) {   // tid<128 = 2 full waves
            sl += __shfl_xor(sl, off);
            sc += __shfl_xor(sc, off);
        }
        if ((tid & 63) == 0) {
            const float inv = 1.0f / (float)(Bsz * Tsz);
            atomicAdd(&out[0], sl * inv);  // -loss
            atomicAdd(&out[1], sc * inv);  // accuracy
        }
    }
}

extern "C" void kernel_launch(void* const* d_in, const int* in_sizes, int n_in,
                              void* d_out, int out_size, void* d_ws, size_t ws_size,
                              hipStream_t stream) {
    const float* P = (const float*)d_in[0];  // predictions [B,T,D]
    const float* X = (const float*)d_in[1];  // x_future_encoded [B,T,D]
    float* out = (float*)d_out;

    const size_t ncol  = (size_t)Bsz * Tsz;          // 12288
    const size_t nslot = ncol * NIB;                 // 98304
    const size_t nel   = (size_t)Bsz * Tsz * Dsz;    // 6,291,456

    float* pm   = (float*)d_ws;
    float* ps   = pm + nslot;
    int*   pa   = (int*)(ps + nslot);
    float* diag = (float*)(pa + nslot);
    int*   tickets = (int*)(diag + ncol);
    _Float16* Ph = (_Float16*)(tickets + 96);        // byte offset 1,229,184 (16B aligned)
    _Float16* Pl = Ph + nel;
    _Float16* Xh = Pl + nel;
    _Float16* Xl = Xh + nel;                         // total ws ~51.6 MB

    convert_kernel<<<dim3(2048), dim3(256), 0, stream>>>(P, X, Ph, Pl, Xh, Xl, out, tickets);

    gemm_fused_kernel<<<dim3(NIB, NJB, Tsz), dim3(256), 0, stream>>>(
        Ph, Pl, Xh, Xl, pm, ps, pa, diag, tickets, out);
}

// Round 4
// 138.401 us; speedup vs baseline: 1.7569x; 1.7569x over previous
//
#include <hip/hip_runtime.h>
#include <cstdint>
#include <cstddef>

// Problem constants: B=1024, T=12, D=512
#define Bsz 1024
#define Tsz 12
#define Dsz 512

#define BM 128           // j tile (rows of P)
#define BN 128           // i tile (rows of X)
#define BK 32            // fp32 k per stage
#define NIB (Bsz / BN)   // 8 i-tiles
#define NJB (Bsz / BM)   // 8 j-tiles
#define NKS (Dsz / BK)   // 16 K-steps

typedef _Float16 f16x8 __attribute__((ext_vector_type(8)));
typedef float    f32x4 __attribute__((ext_vector_type(4)));

// async global->LDS, 16B per lane; LDS dest is wave-uniform base + lane*16.
__device__ __forceinline__ void gload_lds16(const float* g, float* l) {
    __builtin_amdgcn_global_load_lds(
        (const __attribute__((address_space(1))) void*)g,
        (__attribute__((address_space(3))) void*)l, 16, 0, 0);
}

// Read 8 consecutive fp32 (k = quad*8 .. quad*8+7) of row `row` from the
// granule-swizzled LDS tile (phys granule = logical granule ^ (row&7)), and
// split to f16 hi/lo in registers. Same hi/lo arithmetic as the passing
// rounds: hi = rne(x), lo = rne(x - hi).
__device__ __forceinline__ void read_conv(const float* s, int row, int quad,
                                          f16x8& ho, f16x8& lo) {
    const int rs = row & 7;
    const float* rp = s + row * BK;
    const f32x4 v0 = *(const f32x4*)(rp + ((((quad << 1)    ) ^ rs) << 2));
    const f32x4 v1 = *(const f32x4*)(rp + ((((quad << 1) | 1) ^ rs) << 2));
    f16x8 h, l;
#pragma unroll
    for (int e = 0; e < 4; ++e) {
        const float a = v0[e], b = v1[e];
        const _Float16 ha = (_Float16)a, hb = (_Float16)b;
        h[e]     = ha;
        h[e + 4] = hb;
        l[e]     = (_Float16)(a - (float)ha);
        l[e + 4] = (_Float16)(b - (float)hb);
    }
    ho = h; lo = l;
}

// Fused GEMM + tile softmax-partials. dots[t,i,j] = <P[j,t,:], X[i,t,:]>.
// 128x128 tile, 4 waves (2x2), each wave owns a 64x64 sub-tile: acc[4][4]
// of 16x16 fragments (round-3 bug: acc[4][2] left i%64 in 32..63 uncomputed
// and diag unwritten for those j -> absmax 4.5). 16x16x32 MFMA, fp32 staged
// via global_load_lds dwordx4 with granule XOR swizzle baked into the GLOBAL
// source (linear LDS dest, rule #21) + same XOR on the read side ->
// conflict-free. fp32->f16 hi/lo split in registers post-ds_read. Double-
// buffered LDS, ONE barrier per K-step: next-tile loads issue before
// current-tile compute, so ~500-900 cyc load latency hides under compute.
__global__ __launch_bounds__(256, 2) void gemm_fused_kernel(
    const float* __restrict__ P,   // predictions      [B,T,D] (j rows, A side)
    const float* __restrict__ X,   // x_future_encoded [B,T,D] (i rows, B side)
    float* __restrict__ pm,        // [Tsz*Bsz*NIB] tile max
    float* __restrict__ ps,        // [Tsz*Bsz*NIB] tile sum exp
    int*   __restrict__ pa,        // [Tsz*Bsz*NIB] tile argmax (global i)
    float* __restrict__ diag,      // [Tsz*Bsz]
    float* __restrict__ out)       // [2] zeroed here (block 0) for combine
{
    // ---- XCD-chunked bijective remap (768 % 8 == 0): each XCD gets 96
    // consecutive t-major tiles -> per-t working set (8 MB fp32) L2-resident.
    // Evidence: FETCH 130 MB -> 29.6 MB in round 2.
    const int orig = blockIdx.x + (blockIdx.y << 3) + (blockIdx.z << 6);
    const int wgid = (orig & 7) * 96 + (orig >> 3);
    const int t   = wgid >> 6;       // t-major: 64 tiles per t-plane
    const int rem = wgid & 63;
    const int by  = rem >> 3;        // j tile
    const int bx  = rem & 7;         // i tile (fastest -> P-panel L2 reuse)
    const int ib = bx * BN;
    const int jb = by * BM;

    const int tid  = threadIdx.x;
    const int lane = tid & 63;
    const int w    = tid >> 6;          // wave 0..3
    const int jw   = (w >> 1) * 64;     // wave j-offset
    const int iw   = (w & 1) * 64;      // wave i-offset
    const int ml   = lane & 15;
    const int quad = lane >> 4;

    if (orig == 0 && tid < 2) out[tid] = 0.0f;   // combine runs in next kernel

    __shared__ float Ab[2][BM][BK];   // P tile, 2 x 16 KB
    __shared__ float Bb[2][BN][BK];   // X tile, 2 x 16 KB
    __shared__ float sm_m[BM][2];
    __shared__ float sm_s[BM][2];
    __shared__ int   sm_a[BM][2];

    f32x4 acc[4][4];
#pragma unroll
    for (int r = 0; r < 4; ++r)
#pragma unroll
        for (int c = 0; c < 4; ++c) acc[r][c] = (f32x4){0.f, 0.f, 0.f, 0.f};

    // ---- staging setup: waves 0,1 -> P rows 0-63/64-127; waves 2,3 -> X.
    // Lane l of instr h covers row rowbase+h*8+(l>>3), phys granule l&7;
    // source granule = (l&7) ^ (row&7) = (l&7) ^ (l>>3)  (8-aligned bases).
    const float* src = (w & 2) ? X : P;
    const int rb = ((w & 2) ? ib : jb) + (w & 1) * 64;
    const int lr = lane >> 3;                    // 0..7
    const int sg = (lane & 7) ^ lr;              // source fp32-granule (x4 floats)
    const size_t strideRow = (size_t)Tsz * Dsz;  // 6144 floats
    const float* gsrc = src + (size_t)(rb + lr) * strideRow + (size_t)t * Dsz + (sg << 2);
    float* lbase = (w & 2) ? &Bb[0][0][0] : &Ab[0][0][0];
    const int lrow0 = (w & 1) * 64;              // wave's first row in tile

#define STAGE(bsel, k0f)                                                      \
    do {                                                                      \
        float* d_ = lbase + (size_t)(bsel) * (BM * BK) + (size_t)lrow0 * BK;  \
        const float* s_ = gsrc + (k0f);                                       \
        _Pragma("unroll")                                                     \
        for (int h_ = 0; h_ < 8; ++h_)                                        \
            gload_lds16(s_ + (size_t)h_ * 8 * strideRow, d_ + h_ * 8 * BK);   \
    } while (0)

    STAGE(0, 0);
    __syncthreads();     // compiler drains vmcnt(0) before s_barrier

    int bsel = 0;
    for (int ks = 0; ks < NKS; ++ks) {
        // ---- issue next-tile loads FIRST: latency hides under compute ----
        if (ks + 1 < NKS) STAGE(bsel ^ 1, (ks + 1) * BK);

        const float* As = &Ab[bsel][0][0];
        const float* Bs = &Bb[bsel][0][0];

        // ---- fragments: swizzled fp32 reads + in-reg hi/lo split ----
        f16x8 ah[4], al[4], bh[4], bl[4];
#pragma unroll
        for (int r = 0; r < 4; ++r) read_conv(As, jw + r * 16 + ml, quad, ah[r], al[r]);
#pragma unroll
        for (int c = 0; c < 4; ++c) read_conv(Bs, iw + c * 16 + ml, quad, bh[c], bl[c]);

        // ---- MFMA: hi*hi + hi*lo + lo*hi (same order as passing rounds) ----
#pragma unroll
        for (int r = 0; r < 4; ++r)
#pragma unroll
            for (int c = 0; c < 4; ++c) {
                acc[r][c] = __builtin_amdgcn_mfma_f32_16x16x32_f16(ah[r], bh[c], acc[r][c], 0, 0, 0);
                acc[r][c] = __builtin_amdgcn_mfma_f32_16x16x32_f16(ah[r], bl[c], acc[r][c], 0, 0, 0);
                acc[r][c] = __builtin_amdgcn_mfma_f32_16x16x32_f16(al[r], bh[c], acc[r][c], 0, 0, 0);
            }

        __syncthreads();   // drains next-tile vmem + this tile's LDS reads
        bsel ^= 1;
    }
#undef STAGE

    // ---- diag extraction (global index test; epilogue-only) ----
#pragma unroll
    for (int r = 0; r < 4; ++r)
#pragma unroll
        for (int v = 0; v < 4; ++v) {
            const int jg = jb + jw + r * 16 + quad * 4 + v;
#pragma unroll
            for (int c = 0; c < 4; ++c) {
                const int ig = ib + iw + c * 16 + ml;
                if (ig == jg) diag[(size_t)t * Bsz + jg] = acc[r][c][v];
            }
        }

    // ---- per-row (j) partial over this wave's 64-i slice ----
    // acc[r][c][v]: row j = jw+r*16+quad*4+v, col i = iw+c*16+ml.
#pragma unroll
    for (int r = 0; r < 4; ++r)
#pragma unroll
        for (int v = 0; v < 4; ++v) {
            float m = acc[r][0][v];
            int   ai = iw + ml;
#pragma unroll
            for (int c = 1; c < 4; ++c) {
                const float val = acc[r][c][v];
                if (val > m) { m = val; ai = iw + c * 16 + ml; }  // ascending c -> ties keep smaller i
            }
#pragma unroll
            for (int off = 1; off < 16; off <<= 1) {
                const float om = __shfl_xor(m, off);
                const int   oi = __shfl_xor(ai, off);
                if (om > m || (om == m && oi < ai)) { m = om; ai = oi; }
            }
            float s = 0.0f;
#pragma unroll
            for (int c = 0; c < 4; ++c) s += __expf(acc[r][c][v] - m);
#pragma unroll
            for (int off = 1; off < 16; off <<= 1) s += __shfl_xor(s, off);

            if (ml == 0) {
                const int row = jw + r * 16 + quad * 4 + v;
                sm_m[row][iw >> 6] = m;
                sm_s[row][iw >> 6] = s;
                sm_a[row][iw >> 6] = ib + ai;   // global i
            }
        }
    __syncthreads();

    // ---- combine the two i-halves, write tile partials ----
    if (tid < BM) {
        const int row = tid;
        const float m0 = sm_m[row][0], m1 = sm_m[row][1];
        const float s0 = sm_s[row][0], s1 = sm_s[row][1];
        float M; int A;
        if (m1 > m0) { M = m1; A = sm_a[row][1]; }   // tie -> half 0 (smaller i)
        else         { M = m0; A = sm_a[row][0]; }
        const float S = s0 * __expf(m0 - M) + s1 * __expf(m1 - M);
        const size_t slot = ((size_t)t * Bsz + (jb + row)) * NIB + bx;
        pm[slot] = M;
        ps[slot] = S;
        pa[slot] = A;
    }
}

// One thread per (t,j) column: merge NIB tile partials, 48 block atomics.
__global__ __launch_bounds__(256) void combine_kernel(
    const float* __restrict__ pm,
    const float* __restrict__ ps,
    const int*   __restrict__ pa,
    const float* __restrict__ diag,
    float* __restrict__ out)
{
    const int col = blockIdx.x * 256 + threadIdx.x;   // 0..Tsz*Bsz-1
    const int j = col & (Bsz - 1);

    const size_t base = (size_t)col * NIB;
    float M = pm[base]; int A = pa[base];
#pragma unroll
    for (int b = 1; b < NIB; ++b) {
        const float mb = pm[base + b];
        if (mb > M) { M = mb; A = pa[base + b]; }   // tie -> earlier b = smaller i
    }
    float S = 0.0f;
#pragma unroll
    for (int b = 0; b < NIB; ++b) S += ps[base + b] * __expf(pm[base + b] - M);

    const float lse = M + logf(S);
    float sl = lse - diag[col];
    float sc = (A == j) ? 1.0f : 0.0f;

#pragma unroll
    for (int off = 1; off < 64; off <<= 1) {
        sl += __shfl_xor(sl, off);
        sc += __shfl_xor(sc, off);
    }

    __shared__ float wl[4], wc[4];
    const int w = threadIdx.x >> 6;
    if ((threadIdx.x & 63) == 0) { wl[w] = sl; wc[w] = sc; }
    __syncthreads();
    if (threadIdx.x == 0) {
        const float inv = 1.0f / (float)(Bsz * Tsz);
        atomicAdd(&out[0], (wl[0] + wl[1] + wl[2] + wl[3]) * inv);  // -loss
        atomicAdd(&out[1], (wc[0] + wc[1] + wc[2] + wc[3]) * inv);  // accuracy
    }
}

extern "C" void kernel_launch(void* const* d_in, const int* in_sizes, int n_in,
                              void* d_out, int out_size, void* d_ws, size_t ws_size,
                              hipStream_t stream) {
    const float* P = (const float*)d_in[0];  // predictions [B,T,D]
    const float* X = (const float*)d_in[1];  // x_future_encoded [B,T,D]
    float* out = (float*)d_out;

    const size_t ncol  = (size_t)Bsz * Tsz;          // 12288
    const size_t nslot = ncol * NIB;                 // 98304

    float* pm   = (float*)d_ws;
    float* ps   = pm + nslot;
    int*   pa   = (int*)(ps + nslot);
    float* diag = (float*)(pa + nslot);              // total ws ~1.23 MB

    gemm_fused_kernel<<<dim3(NIB, NJB, Tsz), dim3(256), 0, stream>>>(
        P, X, pm, ps, pa, diag, out);

    combine_kernel<<<dim3((int)(ncol / 256)), dim3(256), 0, stream>>>(
        pm, ps, pa, diag, out);
}